// Round 4
// baseline (124.853 us; speedup 1.0000x reference)
//
#include <hip/hip_runtime.h>

// PostProcessor3D: threshold(>0.9) + 5x5x5 stride-1 maxpool + strict-local-max
// mask on [64,512,512] fp32.
//
// R15: REGISTER-DIRECT data path -- no LDS, no DMA, no barriers, no asm waits.
// Post-mortem R11-R14: three different sync schemes (barrier+drain,
// barrier+counted-vmcnt, zero-barrier per-wave vmcnt) all land 45-56 us with
// every pipe <=42% -- the invariant is the LDS round-trip on every slice's
// critical path and hand-imposed dist-1 waits that can't cover L2/HBM latency
// (vmcnt retires in order; each slice queues behind older completions).
// The 6.3 TB/s copy ubench (m13) has none of that: plain vectorized global
// loads -> regs -> stores, deep independence. Make this kernel be that:
//  (a) Each lane global-loads its own 5-row H-window (5x float4 at
//      precomputed clamped row offsets) per slice. Row redundancy (20
//      row-segments per 8 unique rows per wave) is L1/L2-absorbed --
//      FETCH_SIZE will confirm or refute.
//  (b) W-halo: 8 edge lanes (tx==0/15) load 5x float2 (exec-masked branch).
//      True W-edges zero the halo taps (valid: all raws >= 0, center > 0.9).
//  (c) Clamp-replicate in H and D (max over duplicated in-window rows/slices
//      is unchanged) -> no bounds predication on the load path.
//  (d) NO hand scheduling: fully unrolled NS=12 loop, compiler assigns
//      vmcnt and pipelines slices as deep as registers allow.
//      __attribute__((amdgpu_num_vgpr(128))) caps at the 4-waves/SIMD
//      bucket edge (insurance vs runaway pipelining; R12: spills are
//      catastrophic, so cap at bucket edge, never below natural alloc).
//  (e) Proven consume machinery unchanged: wmax5s + 4 shuffles for W,
//      win[5] D-ring, cen[2] center ring, nontemporal 16B stores.
//
// Tile: wave W64 x H4 (block 16x16 = 4 waves, H16), DCHUNK=8
//       -> grid 8 x 32 x 8 = 2048 blocks.

#define THRESH 0.9f

constexpr int D = 64, H = 512, W = 512;
constexpr int HW = H * W;
constexpr int TW = 64;                    // tile width (floats)
constexpr int TH = 16;                    // tile height (rows)
constexpr int DCHUNK = 8;                 // depth outputs per block
constexpr int HALO = 2;
constexpr int NS = DCHUNK + 2 * HALO;     // 12 slices per block

typedef float floatx4 __attribute__((ext_vector_type(4)));

__device__ __forceinline__ float4 max4(float4 a, float4 b) {
    return make_float4(fmaxf(a.x, b.x), fmaxf(a.y, b.y),
                       fmaxf(a.z, b.z), fmaxf(a.w, b.w));
}

// 5-tap sliding max for one quad. b = own (f4..f7), f2,f3 = left neighbor's
// .z,.w; f8,f9 = right neighbor's .x,.y. out[j] = max over [4c+j-2, 4c+j+2].
__device__ __forceinline__ float4 wmax5s(float f2, float f3, float4 b,
                                         float f8, float f9) {
    const float f4 = b.x, f5 = b.y, f6 = b.z, f7 = b.w;
    const float m45 = fmaxf(f4, f5);
    const float m56 = fmaxf(f5, f6);
    const float m345 = fmaxf(f3, m45);
    const float m456 = fmaxf(f4, m56);
    const float m567 = fmaxf(m56, f7);
    const float m678 = fmaxf(fmaxf(f6, f7), f8);
    float4 r;
    r.x = fmaxf(fmaxf(f2, f6), m345);
    r.y = fmaxf(fmaxf(f3, f7), m456);
    r.z = fmaxf(fmaxf(f4, f8), m567);
    r.w = fmaxf(fmaxf(f5, f9), m678);
    return r;
}

__global__ __launch_bounds__(256)
__attribute__((amdgpu_num_vgpr(128)))
void peak3d_kernel(const float* __restrict__ in, float* __restrict__ out) {
    const int tx = threadIdx.x;           // 0..15 (quad col)
    const int tyb = threadIdx.y;          // 0..15 (row in block tile)

    const int w0 = blockIdx.x * TW;
    const int h0 = blockIdx.y * TH;
    const int d0 = blockIdx.z * DCHUNK;

    const int ty = h0 + tyb;              // global output row
    const int col = w0 + 4 * tx;          // global output col (quad start)

    const bool isL = (tx == 0), isR = (tx == 15);
    const bool edgeW = (isL && w0 == 0) || (isR && w0 == W - TW);
    // Halo column pair: left edge lanes read cols w0-2,w0-1; right edge
    // lanes read cols w0+64,w0+65 (clamped; true edges zeroed below).
    const int hcol = isL ? max(w0 - 2, 0) : min(w0 + TW, W - 2);

    // Per-lane H-clamped row offsets (z-independent, computed once).
    int off[5], hoff[5];
#pragma unroll
    for (int k = 0; k < 5; ++k) {
        const int gh = min(max(ty + k - HALO, 0), H - 1);  // clamp-replicate
        off[k] = gh * W + col;
        hoff[k] = gh * W + hcol;
    }

    const float4 zero4 = make_float4(0.f, 0.f, 0.f, 0.f);
    float4 win[5];                        // HW-max ring, depth 5 (D window)
    float4 cen[2];                        // raw center ring, depth 2
#pragma unroll
    for (int k = 0; k < 5; ++k) win[k] = zero4;
    cen[0] = zero4; cen[1] = zero4;

#pragma unroll
    for (int t = 0; t < NS; ++t) {        // fully unrolled: t constant
        // Slice base (D clamp-replicate).
        const float* sb = in + min(max(d0 - HALO + t, 0), D - 1) * HW;

        // ---- 5-row H-window, direct to registers ----
        const float4 r0 = *reinterpret_cast<const float4*>(sb + off[0]);
        const float4 r1 = *reinterpret_cast<const float4*>(sb + off[1]);
        const float4 r2 = *reinterpret_cast<const float4*>(sb + off[2]);
        const float4 r3 = *reinterpret_cast<const float4*>(sb + off[3]);
        const float4 r4 = *reinterpret_cast<const float4*>(sb + off[4]);

        // ---- W-halo pair, H-maxed (edge lanes only, exec-masked) ----
        float2 h = make_float2(0.f, 0.f);
        if (isL || isR) {
            const float2 e0 = *reinterpret_cast<const float2*>(sb + hoff[0]);
            const float2 e1 = *reinterpret_cast<const float2*>(sb + hoff[1]);
            const float2 e2 = *reinterpret_cast<const float2*>(sb + hoff[2]);
            const float2 e3 = *reinterpret_cast<const float2*>(sb + hoff[3]);
            const float2 e4 = *reinterpret_cast<const float2*>(sb + hoff[4]);
            h.x = fmaxf(fmaxf(fmaxf(e0.x, e1.x), fmaxf(e3.x, e4.x)), e2.x);
            h.y = fmaxf(fmaxf(fmaxf(e0.y, e1.y), fmaxf(e3.y, e4.y)), e2.y);
            if (edgeW) { h.x = 0.f; h.y = 0.f; }   // true OOB in W: pad 0
        }

        // ---- H-max fold ----
        const float4 hv = max4(max4(max4(r0, r1), max4(r3, r4)), r2);

        // ---- W-max via shuffles on H-maxed quads ----
        float f2 = __shfl_up(hv.z, 1);
        float f3 = __shfl_up(hv.w, 1);
        float f8 = __shfl_down(hv.x, 1);
        float f9 = __shfl_down(hv.y, 1);
        if (isL) { f2 = h.x; f3 = h.y; }
        if (isR) { f8 = h.x; f9 = h.y; }

        win[t % 5] = wmax5s(f2, f3, hv, f8, f9);   // HW-max, slice t

        // ---- D-max + strict-local-max + store (center = slice t-2) ----
        if (t >= 4) {
            const int dout = d0 + (t - 4);
            const float4 mp = max4(max4(max4(win[0], win[1]),
                                        max4(win[2], win[3])), win[4]);
            const float4 c = cen[t & 1];           // written at iter t-2
            floatx4 res;
            res.x = (c.x > THRESH && mp.x == c.x) ? c.x : 0.f;
            res.y = (c.y > THRESH && mp.y == c.y) ? c.y : 0.f;
            res.z = (c.z > THRESH && mp.z == c.z) ? c.z : 0.f;
            res.w = (c.w > THRESH && mp.w == c.w) ? c.w : 0.f;
            floatx4* op = reinterpret_cast<floatx4*>(
                out + (size_t)(dout * HW + ty * W + col));
            __builtin_nontemporal_store(res, op);
        }
        cen[t & 1] = r2;                           // write AFTER read above
    }
}

extern "C" void kernel_launch(void* const* d_in, const int* in_sizes, int n_in,
                              void* d_out, int out_size, void* d_ws, size_t ws_size,
                              hipStream_t stream) {
    const float* in = (const float*)d_in[0];
    float* out = (float*)d_out;
    dim3 grid(W / TW, H / TH, D / DCHUNK);    // 8 x 32 x 8 = 2048 blocks
    dim3 block(16, 16, 1);
    hipLaunchKernelGGL(peak3d_kernel, grid, block, 0, stream, in, out);
}

// Round 5
// 118.406 us; speedup vs baseline: 1.0544x; 1.0544x over previous
//
#include <hip/hip_runtime.h>
#include <stdint.h>
#include <utility>

// PostProcessor3D: threshold(>0.9) + 5x5x5 stride-1 maxpool + strict-local-max
// mask on [64,512,512] fp32.
//
// R16: DIST-3 DMA PREFETCH into a 5-deep LDS ring with exact counted vmcnt.
// Unified post-mortem R11-R15: all variants had effective prefetch distance
// <=1 slice (R13's vmcnt(1) drained BOTH loads of the next slice: outstanding
// at the wait was {2 loads, 1 store} and vmcnt retires oldest-first). Each
// wave exposed one L2/HBM round-trip per slice -> ~45-55 us invariant at
// <42% on every pipe. R12 (spill storm) showed max in-flight traffic = max
// realized BW. Fix: prefetch depth that registers can't afford but LDS-DMA
// gives for free:
//  (a) raw[5][384] LDS ring (30.7 KB); at iter t: issue DMA for slice t+3,
//      wait a count that retires ONLY ops >=3 iters old, barrier, consume
//      slice t from raw[t%5]. Steady-state wait = vmcnt(9) big / (6) small.
//  (b) WAR safety with ONE barrier/slice: buf t%5's next writer is L(t+5)
//      at iter t+2, after barrier(t+1), which follows all reads of t%5.
//  (c) Staging 6 chunks of 64 slots (384 >= 360 real): waves 0-1 stage 2
//      chunks, waves 2-3 one -> fewer trash loads than R13 (24 vs 152).
//      Per-wave wait counts via wave-uniform branch (template immediates,
//      integral_constant unroll keeps them parse-time constants).
//  (d) DCHUNK=16 -> grid 8x32x4 = 1024 blocks = 4/CU all-resident, no tail;
//      z-halo 20/16 = 1.25x staging, partly L2-absorbed.
//  (e) Proven R13 consume machinery unchanged (raw-max trick, H-max direct
//      from LDS + halo column, W-max via 4 shuffles, win[5]/cen[2] rings,
//      clamp-replicate loads, nontemporal stores). VGPR cap 64 kept.

#define THRESH 0.9f

constexpr int D = 64, H = 512, W = 512;
constexpr int HW = H * W;
constexpr int TW = 64;                    // tile width (floats)
constexpr int TH = 16;                    // tile height
constexpr int DCHUNK = 16;                // depth outputs per block
constexpr int HALO = 2;
constexpr int LROWS = TH + 2 * HALO;      // 20 staged rows
constexpr int RAWQ = TW / 4 + 2;          // 18 quads/row (linear, DMA dest)
constexpr int NQ = LROWS * RAWQ;          // 360 real quads
constexpr int SLOTS = 384;                // 6 chunks x 64 lanes
constexpr int DEPTH = 5;                  // LDS ring depth (dist-3 + WAR)
constexpr int NS = DCHUNK + 2 * HALO;     // 20 slices per block

typedef float floatx4 __attribute__((ext_vector_type(4)));
using gu32p = const __attribute__((address_space(1))) uint32_t*;
using lu32p = __attribute__((address_space(3))) uint32_t*;

__device__ __forceinline__ float4 max4(float4 a, float4 b) {
    return make_float4(fmaxf(a.x, b.x), fmaxf(a.y, b.y),
                       fmaxf(a.z, b.z), fmaxf(a.w, b.w));
}

// 5-tap sliding max for one quad. b = own (f4..f7), f2,f3 = left neighbor's
// .z,.w; f8,f9 = right neighbor's .x,.y. out[j] = max over [4c+j-2, 4c+j+2].
__device__ __forceinline__ float4 wmax5s(float f2, float f3, float4 b,
                                         float f8, float f9) {
    const float f4 = b.x, f5 = b.y, f6 = b.z, f7 = b.w;
    const float m45 = fmaxf(f4, f5);
    const float m56 = fmaxf(f5, f6);
    const float m345 = fmaxf(f3, m45);
    const float m456 = fmaxf(f4, m56);
    const float m567 = fmaxf(m56, f7);
    const float m678 = fmaxf(fmaxf(f6, f7), f8);
    float4 r;
    r.x = fmaxf(fmaxf(f2, f6), m345);
    r.y = fmaxf(fmaxf(f3, f7), m456);
    r.z = fmaxf(fmaxf(f4, f8), m567);
    r.w = fmaxf(fmaxf(f5, f9), m678);
    return r;
}

template <int N>
__device__ __forceinline__ void cwait() {   // counted vmcnt, no lgkm/exp wait
    asm volatile("s_waitcnt vmcnt(%0)" :: "n"(N) : "memory");
}

template <typename F, int... I>
__device__ __forceinline__ void static_for_impl(F&& f,
                                                std::integer_sequence<int, I...>) {
    (f(std::integral_constant<int, I>{}), ...);
}
template <int N, typename F>
__device__ __forceinline__ void static_for(F&& f) {
    static_for_impl(static_cast<F&&>(f), std::make_integer_sequence<int, N>{});
}

__global__ __launch_bounds__(256)
__attribute__((amdgpu_num_vgpr(64)))
void peak3d_kernel(const float* __restrict__ in, float* __restrict__ out) {
    __shared__ float4 raw[DEPTH][SLOTS];  // 5 x 6144 B = 30720 B

    const int tid = threadIdx.y * 16 + threadIdx.x;
    const int wid = tid >> 6;             // wave 0..3
    const int lane = tid & 63;
    const int tx = tid & 15;              // quad col 0..15
    const int ty = tid >> 4;              // row 0..15

    const int w0 = blockIdx.x * TW;
    const int h0 = blockIdx.y * TH;
    const int d0 = blockIdx.z * DCHUNK;

    // Staging: chunk A = wid (all waves), chunk B = 4+wid (waves 0,1 only).
    // Slot s -> (row, col) = (s/18, s%18); trash slots (>=360) clamp source.
    const bool hasB = (wid < 2);
    const int sA = min(64 * wid + lane, NQ - 1);
    const int sB = min(64 * (4 + wid) + lane, NQ - 1);
    const int rA = sA / RAWQ, cA = sA % RAWQ;
    const int rB = sB / RAWQ, cB = sB % RAWQ;
    const int ghA = min(max(h0 + rA - HALO, 0), H - 1);   // clamp-replicate
    const int gwA = min(max(w0 + 4 * cA - 4, 0), W - 4);
    const int ghB = min(max(h0 + rB - HALO, 0), H - 1);
    const int gwB = min(max(w0 + 4 * cB - 4, 0), W - 4);
    const int offA = ghA * W + gwA;
    const int offB = ghB * W + gwB;

    // Consume-phase indices (R13 proven).
    const int rbase = ty * RAWQ + tx + 1;          // + rr*RAWQ, rr=0..4
    const bool isL = (tx == 0), isR = (tx == 15);
    const bool edgeW = (isL && w0 == 0) || (isR && w0 == W - TW);
    const int hbase = (ty * RAWQ + (isL ? 0 : RAWQ - 1)) * 2 + (isL ? 1 : 0);

    const float4 zero4 = make_float4(0.f, 0.f, 0.f, 0.f);
    float4 win[5];                        // HW-max ring, depth 5 (D window)
    float4 cen[2];                        // raw center ring, depth 2
#pragma unroll
    for (int k = 0; k < 5; ++k) win[k] = zero4;
    cen[0] = zero4; cen[1] = zero4;

    // Issue DMA for slice t into raw[t % DEPTH]. Wave-uniform LDS base.
    auto stage = [&](int t) {
        const int dd = min(max(d0 - HALO + t, 0), D - 1);
        const float* sp = in + dd * HW;
        float4* ldsb = &raw[t % DEPTH][0];
        __builtin_amdgcn_global_load_lds((gu32p)(sp + offA),
                                         (lu32p)(ldsb + 64 * wid), 16, 0, 0);
        if (hasB)
            __builtin_amdgcn_global_load_lds((gu32p)(sp + offB),
                                             (lu32p)(ldsb + 64 * (4 + wid)),
                                             16, 0, 0);
    };

    // Prologue: 3 slices in flight (dist-3).
    stage(0); stage(1); stage(2);

    static_for<NS>([&](auto tc) {
        constexpr int t = decltype(tc)::value;

        if (t + 3 < NS) stage(t + 3);     // keep 3 slices ahead

        // ---- counted wait: retire ONLY ops >= 3 iters old ----
        // After L(t): loads for slices (t, min(t+3, NS-1)] (2 or 1 ops each)
        // + stores for iters [max(4, t-3), t-1].
        constexpr int la = (t + 3 <= NS - 1) ? 3 : (NS - 1 - t);
        constexpr int lo = (t - 3 > 4) ? (t - 3) : 4;
        constexpr int sa = (t - 1 >= lo) ? (t - 1 - lo + 1) : 0;
        if (hasB) cwait<2 * la + sa>(); else cwait<la + sa>();
        asm volatile("s_barrier" ::: "memory");

        // ---- consume: H-max (5 rows) from LDS ring ----
        const float4* bp = &raw[t % DEPTH][0];
        const float4 r0q = bp[rbase + 0 * RAWQ];
        const float4 r1q = bp[rbase + 1 * RAWQ];
        const float4 r2q = bp[rbase + 2 * RAWQ];   // center row (raw)
        const float4 r3q = bp[rbase + 3 * RAWQ];
        const float4 r4q = bp[rbase + 4 * RAWQ];
        const float4 hv = max4(max4(max4(r0q, r1q), max4(r3q, r4q)), r2q);

        // ---- halo H-max: edge lanes only ----
        float2 h = make_float2(0.f, 0.f);
        if (isL || isR) {
            const float2* hp = reinterpret_cast<const float2*>(bp);
            const float2 e0 = hp[hbase + 0 * RAWQ * 2];
            const float2 e1 = hp[hbase + 1 * RAWQ * 2];
            const float2 e2 = hp[hbase + 2 * RAWQ * 2];
            const float2 e3 = hp[hbase + 3 * RAWQ * 2];
            const float2 e4 = hp[hbase + 4 * RAWQ * 2];
            h.x = fmaxf(fmaxf(fmaxf(e0.x, e1.x), fmaxf(e3.x, e4.x)), e2.x);
            h.y = fmaxf(fmaxf(fmaxf(e0.y, e1.y), fmaxf(e3.y, e4.y)), e2.y);
            if (edgeW) { h.x = 0.f; h.y = 0.f; }   // true OOB in W: pad 0
        }

        // ---- W-max via shuffles on H-maxed quads ----
        float f2 = __shfl_up(hv.z, 1);
        float f3 = __shfl_up(hv.w, 1);
        float f8 = __shfl_down(hv.x, 1);
        float f9 = __shfl_down(hv.y, 1);
        if (isL) { f2 = h.x; f3 = h.y; }
        if (isR) { f8 = h.x; f9 = h.y; }

        win[t % 5] = wmax5s(f2, f3, hv, f8, f9);   // HW-max, slice t

        // ---- D-max + strict-local-max + store (center = slice t-2) ----
        if (t >= 4) {
            const int dout = d0 + (t - 4);
            const float4 mp = max4(max4(max4(win[0], win[1]),
                                        max4(win[2], win[3])), win[4]);
            const float4 c = cen[t & 1];           // written at iter t-2
            floatx4 res;
            res.x = (c.x > THRESH && mp.x == c.x) ? c.x : 0.f;
            res.y = (c.y > THRESH && mp.y == c.y) ? c.y : 0.f;
            res.z = (c.z > THRESH && mp.z == c.z) ? c.z : 0.f;
            res.w = (c.w > THRESH && mp.w == c.w) ? c.w : 0.f;
            floatx4* op = reinterpret_cast<floatx4*>(
                out + (size_t)(dout * HW + (h0 + ty) * W + (w0 + 4 * tx)));
            __builtin_nontemporal_store(res, op);
        }
        cen[t & 1] = r2q;                          // write AFTER read above
    });
}

extern "C" void kernel_launch(void* const* d_in, const int* in_sizes, int n_in,
                              void* d_out, int out_size, void* d_ws, size_t ws_size,
                              hipStream_t stream) {
    const float* in = (const float*)d_in[0];
    float* out = (float*)d_out;
    dim3 grid(W / TW, H / TH, D / DCHUNK);    // 8 x 32 x 4 = 1024 blocks
    dim3 block(16, 16, 1);
    hipLaunchKernelGGL(peak3d_kernel, grid, block, 0, stream, in, out);
}

// Round 7
// 118.139 us; speedup vs baseline: 1.0568x; 1.0023x over previous
//
#include <hip/hip_runtime.h>
#include <stdint.h>
#include <utility>

// PostProcessor3D: threshold(>0.9) + 5x5x5 stride-1 maxpool + strict-local-max
// mask on [64,512,512] fp32.
//
// R18 == R17 resubmitted (round 6 was an infra failure: "container failed
// twice", no counters). Kernel re-audited: no deadlock path (zero barriers;
// oversized vmcnt waits pass), LDS/global addressing all in-bounds, masked
// DMA keeps vmcnt wave-uniform. The {dist-3 x zero-barrier} matrix cell is
// still unmeasured and remains the highest-information probe.
//
// R17 rationale: R13-R16 matrix {prefetch depth 1|3} x {barrier convoy
// yes|no}; three tried cells all land ~40-56 us. R14 (no barrier) failed
// because dist-1 can't cover 900-cyc HBM; R16 (dist-3) failed because the
// per-slice 4-wave barrier + asymmetric wait counts re-created the convoy.
// This is the fourth cell: wave-private LDS rings + dist-3 DMA + exact
// counted per-wave vmcnt, no s_barrier anywhere.
//  (a) Each wave owns a W64 x H4 band; stages its 8 halo'd rows (144 quads)
//      into a private 4-deep LDS ring. DEPTH=4 WAR-safe intra-wave: iter t's
//      DMA writes buf[(t+3)%4] = buf[(t-1)%4], whose ds_reads were issued at
//      iter t-1 (before the DMA in program order); DMA data lands >=200 cyc
//      after issue vs ~60 cyc LDS read sampling -> no overlap.
//  (b) 3 DMA/slice/wave: chunks 0,1 full (64 lanes), chunk 2 exec-masked to
//      lane<16 (144 real quads; masked op still issues -> uniform vmcnt).
//  (c) Exact counted wait (R16 machinery, per-wave): at iter t wait
//      vmcnt(3*la + sa), la = loads newer than slice t, sa = stores newer.
//      Steady state vmcnt(12): retires only ops >= 3 slices old; DMA lead
//      ~1200 cyc > 900 cyc HBM miss.
//  (d) LDS 4 waves x 4 bufs x 160 slots x 16 B = 40960 B -> 4 blocks/CU,
//      16 independent waves/CU, ~144 KB VMEM in flight per CU.
//  (e) Proven consume machinery byte-for-byte from R14 (absmax 0): raw-max
//      trick, clamp-replicate, H-max 5x ds_read_b128, halo column, W-max via
//      4 shuffles, win[5]/cen[2] rings, nontemporal stores.
//
// Tile: wave W64 x H4, block 4 waves (H16), DCHUNK=8 -> grid 8x32x8 = 2048.

#define THRESH 0.9f

constexpr int D = 64, H = 512, W = 512;
constexpr int HW = H * W;
constexpr int TW = 64;                    // per-wave tile width (floats)
constexpr int WH = 4;                     // per-wave tile height (rows)
constexpr int NWAVES = 4;                 // waves per block
constexpr int DCHUNK = 8;                 // depth outputs per block
constexpr int HALO = 2;
constexpr int SROWS = WH + 2 * HALO;      // 8 staged rows per wave
constexpr int RAWQ = TW / 4 + 2;          // 18 quads/row
constexpr int NQ = SROWS * RAWQ;          // 144 real quads
constexpr int SLOTS = 160;                // 64+64+32 (chunk2 masked to 16)
constexpr int DEPTH = 4;                  // per-wave LDS ring depth
constexpr int NS = DCHUNK + 2 * HALO;     // 12 slices per block

typedef float floatx4 __attribute__((ext_vector_type(4)));
using gu32p = const __attribute__((address_space(1))) uint32_t*;
using lu32p = __attribute__((address_space(3))) uint32_t*;

__device__ __forceinline__ float4 max4(float4 a, float4 b) {
    return make_float4(fmaxf(a.x, b.x), fmaxf(a.y, b.y),
                       fmaxf(a.z, b.z), fmaxf(a.w, b.w));
}

// 5-tap sliding max for one quad. b = own (f4..f7), f2,f3 = left neighbor's
// .z,.w; f8,f9 = right neighbor's .x,.y. out[j] = max over [4c+j-2, 4c+j+2].
__device__ __forceinline__ float4 wmax5s(float f2, float f3, float4 b,
                                         float f8, float f9) {
    const float f4 = b.x, f5 = b.y, f6 = b.z, f7 = b.w;
    const float m45 = fmaxf(f4, f5);
    const float m56 = fmaxf(f5, f6);
    const float m345 = fmaxf(f3, m45);
    const float m456 = fmaxf(f4, m56);
    const float m567 = fmaxf(m56, f7);
    const float m678 = fmaxf(fmaxf(f6, f7), f8);
    float4 r;
    r.x = fmaxf(fmaxf(f2, f6), m345);
    r.y = fmaxf(fmaxf(f3, f7), m456);
    r.z = fmaxf(fmaxf(f4, f8), m567);
    r.w = fmaxf(fmaxf(f5, f9), m678);
    return r;
}

template <int N>
__device__ __forceinline__ void cwait() {   // counted vmcnt only
    asm volatile("s_waitcnt vmcnt(%0)" :: "n"(N) : "memory");
}

template <typename F, int... I>
__device__ __forceinline__ void static_for_impl(F&& f,
                                                std::integer_sequence<int, I...>) {
    (f(std::integral_constant<int, I>{}), ...);
}
template <int N, typename F>
__device__ __forceinline__ void static_for(F&& f) {
    static_for_impl(static_cast<F&&>(f), std::make_integer_sequence<int, N>{});
}

__global__ __launch_bounds__(256)
__attribute__((amdgpu_num_vgpr(64)))
void peak3d_kernel(const float* __restrict__ in, float* __restrict__ out) {
    __shared__ float4 raw[NWAVES][DEPTH][SLOTS];   // 4*4*160*16 = 40960 B

    const int tid = threadIdx.y * 16 + threadIdx.x;
    const int wid = tid >> 6;             // wave id 0..3
    const int lane = tid & 63;
    const int tx = lane & 15;             // quad col 0..15
    const int tyw = lane >> 4;            // row in band 0..3

    const int w0 = blockIdx.x * TW;
    const int hb = blockIdx.y * (WH * NWAVES) + wid * WH;  // band top row
    const int d0 = blockIdx.z * DCHUNK;

    // 3 per-lane staging source offsets (clamp-replicate).
    int off0, off1, off2;
#pragma unroll
    for (int i = 0; i < 3; ++i) {
        const int s = min(i * 64 + lane, NQ - 1);
        const int r = s / RAWQ, c = s % RAWQ;
        const int gh = min(max(hb + r - HALO, 0), H - 1);
        const int gw = min(max(w0 + 4 * c - 4, 0), W - 4);
        const int o = gh * W + gw;
        if (i == 0) off0 = o; else if (i == 1) off1 = o; else off2 = o;
    }

    // Consume-phase indices (per wave-private region).
    const int rbase = tyw * RAWQ + tx + 1;         // + rr*RAWQ, rr=0..4
    const bool isL = (tx == 0), isR = (tx == 15);
    const bool edgeW = (isL && w0 == 0) || (isR && w0 == W - TW);
    const int hbase = (tyw * RAWQ + (isL ? 0 : RAWQ - 1)) * 2 + (isL ? 1 : 0);

    const float4 zero4 = make_float4(0.f, 0.f, 0.f, 0.f);
    float4 win[5];                        // HW-max ring, depth 5 (D window)
    float4 cen[2];                        // raw center ring, depth 2
#pragma unroll
    for (int k = 0; k < 5; ++k) win[k] = zero4;
    cen[0] = zero4; cen[1] = zero4;

    // Issue 3 DMA loads for slice t into wave-private raw[wid][t%4].
    // LDS dest wave-uniform base (HW adds lane*16); global src per-lane.
    // Chunk 2 is exec-masked to lanes 0..15 (rows 128..143) -- the masked
    // instruction still issues, so vmcnt counts stay wave-uniform.
    auto stage = [&](int t) {
        const int dd = min(max(d0 - HALO + t, 0), D - 1);
        const float* sp = in + dd * HW;
        float4* ldsb = &raw[wid][t & 3][0];
        __builtin_amdgcn_global_load_lds((gu32p)(sp + off0),
                                         (lu32p)(ldsb + 0),   16, 0, 0);
        __builtin_amdgcn_global_load_lds((gu32p)(sp + off1),
                                         (lu32p)(ldsb + 64),  16, 0, 0);
        if (lane < 16)
            __builtin_amdgcn_global_load_lds((gu32p)(sp + off2),
                                             (lu32p)(ldsb + 128), 16, 0, 0);
    };

    // Prologue: 3 slices in flight (dist-3).
    stage(0); stage(1); stage(2);

    static_for<NS>([&](auto tc) {
        constexpr int t = decltype(tc)::value;

        if (t + 3 < NS) stage(t + 3);     // keep 3 slices ahead

        // ---- per-wave counted wait: retire ONLY ops >= 3 slices old ----
        // Newer than L(t): loads for slices (t, min(t+3, NS-1)] (3 ops each)
        // + stores for iters [max(t-3,4), t-1].
        constexpr int la = (NS - 1 - t < 3) ? (NS - 1 - t) : 3;
        constexpr int lo = (t - 3 > 4) ? (t - 3) : 4;
        constexpr int sa = (t - 1 >= lo) ? (t - lo) : 0;
        cwait<3 * la + sa>();

        // ---- consume: H-max (5 rows) from wave-private LDS ring ----
        const float4* bp = &raw[wid][t & 3][0];
        const float4 r0q = bp[rbase + 0 * RAWQ];
        const float4 r1q = bp[rbase + 1 * RAWQ];
        const float4 r2q = bp[rbase + 2 * RAWQ];   // center row (raw)
        const float4 r3q = bp[rbase + 3 * RAWQ];
        const float4 r4q = bp[rbase + 4 * RAWQ];
        const float4 hv = max4(max4(max4(r0q, r1q), max4(r3q, r4q)), r2q);

        // ---- halo H-max: edge lanes only ----
        float2 h = make_float2(0.f, 0.f);
        if (isL || isR) {
            const float2* hp = reinterpret_cast<const float2*>(bp);
            const float2 e0 = hp[hbase + 0 * RAWQ * 2];
            const float2 e1 = hp[hbase + 1 * RAWQ * 2];
            const float2 e2 = hp[hbase + 2 * RAWQ * 2];
            const float2 e3 = hp[hbase + 3 * RAWQ * 2];
            const float2 e4 = hp[hbase + 4 * RAWQ * 2];
            h.x = fmaxf(fmaxf(fmaxf(e0.x, e1.x), fmaxf(e3.x, e4.x)), e2.x);
            h.y = fmaxf(fmaxf(fmaxf(e0.y, e1.y), fmaxf(e3.y, e4.y)), e2.y);
            if (edgeW) { h.x = 0.f; h.y = 0.f; }   // true OOB in W: pad 0
        }

        // ---- W-max via shuffles on H-maxed quads (intra-wave) ----
        float f2 = __shfl_up(hv.z, 1);
        float f3 = __shfl_up(hv.w, 1);
        float f8 = __shfl_down(hv.x, 1);
        float f9 = __shfl_down(hv.y, 1);
        if (isL) { f2 = h.x; f3 = h.y; }
        if (isR) { f8 = h.x; f9 = h.y; }

        win[t % 5] = wmax5s(f2, f3, hv, f8, f9);   // HW-max, slice t

        // ---- D-max + strict-local-max + store (center = slice t-2) ----
        if (t >= 4) {
            const int dout = d0 + (t - 4);
            const float4 mp = max4(max4(max4(win[0], win[1]),
                                        max4(win[2], win[3])), win[4]);
            const float4 c = cen[t & 1];           // written at iter t-2
            floatx4 res;
            res.x = (c.x > THRESH && mp.x == c.x) ? c.x : 0.f;
            res.y = (c.y > THRESH && mp.y == c.y) ? c.y : 0.f;
            res.z = (c.z > THRESH && mp.z == c.z) ? c.z : 0.f;
            res.w = (c.w > THRESH && mp.w == c.w) ? c.w : 0.f;
            floatx4* op = reinterpret_cast<floatx4*>(
                out + (size_t)(dout * HW + (hb + tyw) * W + (w0 + 4 * tx)));
            __builtin_nontemporal_store(res, op);
        }
        cen[t & 1] = r2q;                          // write AFTER read above
    });
}

extern "C" void kernel_launch(void* const* d_in, const int* in_sizes, int n_in,
                              void* d_out, int out_size, void* d_ws, size_t ws_size,
                              hipStream_t stream) {
    const float* in = (const float*)d_in[0];
    float* out = (float*)d_out;
    dim3 grid(W / TW, H / (WH * NWAVES), D / DCHUNK);  // 8 x 32 x 8 = 2048
    dim3 block(16, 16, 1);
    hipLaunchKernelGGL(peak3d_kernel, grid, block, 0, stream, in, out);
}

// Round 8
// 116.131 us; speedup vs baseline: 1.0751x; 1.0173x over previous
//
#include <hip/hip_runtime.h>
#include <stdint.h>
#include <utility>

// PostProcessor3D: threshold(>0.9) + 5x5x5 stride-1 maxpool + strict-local-max
// mask on [64,512,512] fp32.
//
// R19: REQUEST-BYTE reduction on the best measured structure (R16).
// Completed R13-R18 sync matrix: {dist1|dist3} x {barrier|none} = 45.5 /
// 52-56 / ~41-42 / 48.8 us -- sync scheme exhausted. New accounting: the
// per-CU vector-memory REQUEST path (m13 copy ceiling = 10.2 B/cyc/CU
// summed loads+stores) is the invariant limiter: R18 issued 290 MB of
// requests (2.3x the 128 MB minimum, z-halo x1.5 + wave-private h-halo x2)
// = 9.7 B/cyc/CU = 95% of that ceiling. Fix: amortize the z-halo deeper.
//  (a) DCHUNK 16->32 (NS=36): z staging redundancy 36/32 = 1.125x (was
//      20/16 = 1.25x in R16, 12/8 = 1.5x in R18). Request bytes:
//      512 blocks x 36 slices x 6144 B + 64 MB stores = 177 MB (-39% vs
//      R18) -> ~29 us at the path ceiling.
//  (b) grid 8x32x2 = 512 blocks = 2/CU: dispatch-safe (1/CU risks a CU
//      getting 2 and doubling the tail), 8 waves/CU for latency hiding.
//  (c) Everything else is R16 byte-for-byte (its structure ranked best):
//      shared staging 6 chunks x 64 slots (waves 0-1 stage 2 chunks, 2-3
//      one; per-wave exact counted vmcnt via hasB branch), DEPTH-5 LDS
//      ring (30.7 KB), dist-3 DMA prefetch, one s_barrier per slice,
//      raw-max trick, clamp-replicate, H-max direct from LDS + halo
//      column, W-max via 4 shuffles, win[5]/cen[2] rings, nontemporal
//      stores. Full unroll NS=36 (~18 KB code, fits 32 KB L1I) keeps all
//      ring indices compile-time (R3/R12 lesson: spills are catastrophic).
//  (d) WAR safety unchanged: stage(t+3) rewrites buf[(t-2)%5], whose last
//      readers finished before barrier(t-1), one full barrier earlier.
//
// Tile: W=64 x H=16, DCHUNK=32 -> grid 8 x 32 x 2 = 512 blocks, 256 thr.

#define THRESH 0.9f

constexpr int D = 64, H = 512, W = 512;
constexpr int HW = H * W;
constexpr int TW = 64;                    // tile width (floats)
constexpr int TH = 16;                    // tile height
constexpr int DCHUNK = 32;                // depth outputs per block
constexpr int HALO = 2;
constexpr int LROWS = TH + 2 * HALO;      // 20 staged rows
constexpr int RAWQ = TW / 4 + 2;          // 18 quads/row (linear, DMA dest)
constexpr int NQ = LROWS * RAWQ;          // 360 real quads
constexpr int SLOTS = 384;                // 6 chunks x 64 lanes
constexpr int DEPTH = 5;                  // LDS ring depth (dist-3 + WAR)
constexpr int NS = DCHUNK + 2 * HALO;     // 36 slices per block

typedef float floatx4 __attribute__((ext_vector_type(4)));
using gu32p = const __attribute__((address_space(1))) uint32_t*;
using lu32p = __attribute__((address_space(3))) uint32_t*;

__device__ __forceinline__ float4 max4(float4 a, float4 b) {
    return make_float4(fmaxf(a.x, b.x), fmaxf(a.y, b.y),
                       fmaxf(a.z, b.z), fmaxf(a.w, b.w));
}

// 5-tap sliding max for one quad. b = own (f4..f7), f2,f3 = left neighbor's
// .z,.w; f8,f9 = right neighbor's .x,.y. out[j] = max over [4c+j-2, 4c+j+2].
__device__ __forceinline__ float4 wmax5s(float f2, float f3, float4 b,
                                         float f8, float f9) {
    const float f4 = b.x, f5 = b.y, f6 = b.z, f7 = b.w;
    const float m45 = fmaxf(f4, f5);
    const float m56 = fmaxf(f5, f6);
    const float m345 = fmaxf(f3, m45);
    const float m456 = fmaxf(f4, m56);
    const float m567 = fmaxf(m56, f7);
    const float m678 = fmaxf(fmaxf(f6, f7), f8);
    float4 r;
    r.x = fmaxf(fmaxf(f2, f6), m345);
    r.y = fmaxf(fmaxf(f3, f7), m456);
    r.z = fmaxf(fmaxf(f4, f8), m567);
    r.w = fmaxf(fmaxf(f5, f9), m678);
    return r;
}

template <int N>
__device__ __forceinline__ void cwait() {   // counted vmcnt, no lgkm/exp wait
    asm volatile("s_waitcnt vmcnt(%0)" :: "n"(N) : "memory");
}

template <typename F, int... I>
__device__ __forceinline__ void static_for_impl(F&& f,
                                                std::integer_sequence<int, I...>) {
    (f(std::integral_constant<int, I>{}), ...);
}
template <int N, typename F>
__device__ __forceinline__ void static_for(F&& f) {
    static_for_impl(static_cast<F&&>(f), std::make_integer_sequence<int, N>{});
}

__global__ __launch_bounds__(256)
__attribute__((amdgpu_num_vgpr(64)))
void peak3d_kernel(const float* __restrict__ in, float* __restrict__ out) {
    __shared__ float4 raw[DEPTH][SLOTS];  // 5 x 6144 B = 30720 B

    const int tid = threadIdx.y * 16 + threadIdx.x;
    const int wid = tid >> 6;             // wave 0..3
    const int lane = tid & 63;
    const int tx = tid & 15;              // quad col 0..15
    const int ty = tid >> 4;              // row 0..15

    const int w0 = blockIdx.x * TW;
    const int h0 = blockIdx.y * TH;
    const int d0 = blockIdx.z * DCHUNK;

    // Staging: chunk A = wid (all waves), chunk B = 4+wid (waves 0,1 only).
    // Slot s -> (row, col) = (s/18, s%18); trash slots (>=360) clamp source.
    const bool hasB = (wid < 2);
    const int sA = min(64 * wid + lane, NQ - 1);
    const int sB = min(64 * (4 + wid) + lane, NQ - 1);
    const int rA = sA / RAWQ, cA = sA % RAWQ;
    const int rB = sB / RAWQ, cB = sB % RAWQ;
    const int ghA = min(max(h0 + rA - HALO, 0), H - 1);   // clamp-replicate
    const int gwA = min(max(w0 + 4 * cA - 4, 0), W - 4);
    const int ghB = min(max(h0 + rB - HALO, 0), H - 1);
    const int gwB = min(max(w0 + 4 * cB - 4, 0), W - 4);
    const int offA = ghA * W + gwA;
    const int offB = ghB * W + gwB;

    // Consume-phase indices (R13/R16 proven).
    const int rbase = ty * RAWQ + tx + 1;          // + rr*RAWQ, rr=0..4
    const bool isL = (tx == 0), isR = (tx == 15);
    const bool edgeW = (isL && w0 == 0) || (isR && w0 == W - TW);
    const int hbase = (ty * RAWQ + (isL ? 0 : RAWQ - 1)) * 2 + (isL ? 1 : 0);

    const float4 zero4 = make_float4(0.f, 0.f, 0.f, 0.f);
    float4 win[5];                        // HW-max ring, depth 5 (D window)
    float4 cen[2];                        // raw center ring, depth 2
#pragma unroll
    for (int k = 0; k < 5; ++k) win[k] = zero4;
    cen[0] = zero4; cen[1] = zero4;

    // Issue DMA for slice t into raw[t % DEPTH]. Wave-uniform LDS base.
    auto stage = [&](int t) {
        const int dd = min(max(d0 - HALO + t, 0), D - 1);
        const float* sp = in + dd * HW;
        float4* ldsb = &raw[t % DEPTH][0];
        __builtin_amdgcn_global_load_lds((gu32p)(sp + offA),
                                         (lu32p)(ldsb + 64 * wid), 16, 0, 0);
        if (hasB)
            __builtin_amdgcn_global_load_lds((gu32p)(sp + offB),
                                             (lu32p)(ldsb + 64 * (4 + wid)),
                                             16, 0, 0);
    };

    // Prologue: 3 slices in flight (dist-3).
    stage(0); stage(1); stage(2);

    static_for<NS>([&](auto tc) {
        constexpr int t = decltype(tc)::value;

        if (t + 3 < NS) stage(t + 3);     // keep 3 slices ahead

        // ---- counted wait: retire ONLY ops >= 3 iters old ----
        // After L(t): loads for slices (t, min(t+3, NS-1)] (2 or 1 ops each)
        // + stores for iters [max(4, t-3), t-1].
        constexpr int la = (t + 3 <= NS - 1) ? 3 : (NS - 1 - t);
        constexpr int lo = (t - 3 > 4) ? (t - 3) : 4;
        constexpr int sa = (t - 1 >= lo) ? (t - 1 - lo + 1) : 0;
        if (hasB) cwait<2 * la + sa>(); else cwait<la + sa>();
        asm volatile("s_barrier" ::: "memory");

        // ---- consume: H-max (5 rows) from LDS ring ----
        const float4* bp = &raw[t % DEPTH][0];
        const float4 r0q = bp[rbase + 0 * RAWQ];
        const float4 r1q = bp[rbase + 1 * RAWQ];
        const float4 r2q = bp[rbase + 2 * RAWQ];   // center row (raw)
        const float4 r3q = bp[rbase + 3 * RAWQ];
        const float4 r4q = bp[rbase + 4 * RAWQ];
        const float4 hv = max4(max4(max4(r0q, r1q), max4(r3q, r4q)), r2q);

        // ---- halo H-max: edge lanes only ----
        float2 h = make_float2(0.f, 0.f);
        if (isL || isR) {
            const float2* hp = reinterpret_cast<const float2*>(bp);
            const float2 e0 = hp[hbase + 0 * RAWQ * 2];
            const float2 e1 = hp[hbase + 1 * RAWQ * 2];
            const float2 e2 = hp[hbase + 2 * RAWQ * 2];
            const float2 e3 = hp[hbase + 3 * RAWQ * 2];
            const float2 e4 = hp[hbase + 4 * RAWQ * 2];
            h.x = fmaxf(fmaxf(fmaxf(e0.x, e1.x), fmaxf(e3.x, e4.x)), e2.x);
            h.y = fmaxf(fmaxf(fmaxf(e0.y, e1.y), fmaxf(e3.y, e4.y)), e2.y);
            if (edgeW) { h.x = 0.f; h.y = 0.f; }   // true OOB in W: pad 0
        }

        // ---- W-max via shuffles on H-maxed quads ----
        float f2 = __shfl_up(hv.z, 1);
        float f3 = __shfl_up(hv.w, 1);
        float f8 = __shfl_down(hv.x, 1);
        float f9 = __shfl_down(hv.y, 1);
        if (isL) { f2 = h.x; f3 = h.y; }
        if (isR) { f8 = h.x; f9 = h.y; }

        win[t % 5] = wmax5s(f2, f3, hv, f8, f9);   // HW-max, slice t

        // ---- D-max + strict-local-max + store (center = slice t-2) ----
        if (t >= 4) {
            const int dout = d0 + (t - 4);
            const float4 mp = max4(max4(max4(win[0], win[1]),
                                        max4(win[2], win[3])), win[4]);
            const float4 c = cen[t & 1];           // written at iter t-2
            floatx4 res;
            res.x = (c.x > THRESH && mp.x == c.x) ? c.x : 0.f;
            res.y = (c.y > THRESH && mp.y == c.y) ? c.y : 0.f;
            res.z = (c.z > THRESH && mp.z == c.z) ? c.z : 0.f;
            res.w = (c.w > THRESH && mp.w == c.w) ? c.w : 0.f;
            floatx4* op = reinterpret_cast<floatx4*>(
                out + (size_t)(dout * HW + (h0 + ty) * W + (w0 + 4 * tx)));
            __builtin_nontemporal_store(res, op);
        }
        cen[t & 1] = r2q;                          // write AFTER read above
    });
}

extern "C" void kernel_launch(void* const* d_in, const int* in_sizes, int n_in,
                              void* d_out, int out_size, void* d_ws, size_t ws_size,
                              hipStream_t stream) {
    const float* in = (const float*)d_in[0];
    float* out = (float*)d_out;
    dim3 grid(W / TW, H / TH, D / DCHUNK);    // 8 x 32 x 2 = 512 blocks
    dim3 block(16, 16, 1);
    hipLaunchKernelGGL(peak3d_kernel, grid, block, 0, stream, in, out);
}